// Round 1
// baseline (473.767 us; speedup 1.0000x reference)
//
#include <hip/hip_runtime.h>
#include <math.h>

#define BB 2
#define NF 20000
#define NS 30000
#define CH 128
#define NK 500
#define KNN 16

// output offsets (floats, concatenated in return order)
#define OUT0_OFF 0           // out          (B*NK*128) = 128000
#define OUT1_OFF 128000      // key_voxel_indices (B*NK*3) = 3000
#define OUT2_OFF 131000      // heat_scores  (B*NF) = 40000
#define OUT3_OFF 171000      // scores10     (B*NF*10) = 400000
#define OUT4_OFF 571000      // key_class    (B*NK) = 1000

// workspace offsets (bytes)
#define WS_CLS   0           // int32  x 40000  (160000 B)
#define WS_TKI   160000      // int32  x 1000   (4000 B)
#define WS_KW    164000      // float  x 2000   (8000 B)
#define WS_MF    172000      // float  x 256000 (1024000 B)
#define WS_KEYS  1196000     // u64    x 40000  (320000 B)

// ---------------------------------------------------------------------------
// K1: heat MLP.  64 rows/block, 256 threads. Thread t: row r=t/4, phase p=t%3..
// cols c = 16j + 4p + {0..3}, j=0..7 (32 cols). X tile in LDS (stride 132 ->
// 2-way bank alias, free). w1 read from global via float4 (L1/L2 resident).
// ---------------------------------------------------------------------------
__global__ __launch_bounds__(256) void heat_kernel(
    const float* __restrict__ x,      // (B*NF, 128)
    const float* __restrict__ w1,     // (128,128)
    const float* __restrict__ g1, const float* __restrict__ b1,
    const float* __restrict__ w2,     // (128,10)
    const float* __restrict__ b2,     // (10)
    float* __restrict__ out_heat,     // (B*NF)
    float* __restrict__ out_s10,      // (B*NF,10)
    int* __restrict__ cls)            // (B*NF)
{
    __shared__ float Xs[64 * 132];
    __shared__ float W2s[128 * 10];
    const int tid = threadIdx.x;
    const int m0 = blockIdx.x * 64;
    const int mrows = min(64, BB * NF - m0);

    for (int v = tid; v < 1280; v += 256) W2s[v] = w2[v];
    {
        const float4* xv = (const float4*)(x + (size_t)m0 * 128);
        for (int v = tid; v < 64 * 32; v += 256) {
            int row = v >> 5, c4 = v & 31;
            float4 val = (row < mrows) ? xv[v] : make_float4(0.f, 0.f, 0.f, 0.f);
            *((float4*)&Xs[row * 132 + c4 * 4]) = val;
        }
    }
    __syncthreads();

    const int r = tid >> 2;
    const int p = tid & 3;
    float acc[8][4];
#pragma unroll
    for (int j = 0; j < 8; ++j)
#pragma unroll
        for (int i = 0; i < 4; ++i) acc[j][i] = 0.f;

    const float* xrow = &Xs[r * 132];
    const float4* w1v = (const float4*)w1;
#pragma unroll 2
    for (int k = 0; k < 128; ++k) {
        float xk = xrow[k];
        const float4* wrow = w1v + k * 32;
#pragma unroll
        for (int j = 0; j < 8; ++j) {
            float4 w = wrow[j * 4 + p];
            acc[j][0] += xk * w.x;
            acc[j][1] += xk * w.y;
            acc[j][2] += xk * w.z;
            acc[j][3] += xk * w.w;
        }
    }
    __syncthreads();
    // relu((x@w1)*g1 + b1) -> back into Xs
#pragma unroll
    for (int j = 0; j < 8; ++j)
#pragma unroll
        for (int i = 0; i < 4; ++i) {
            int c = j * 16 + p * 4 + i;
            float h = acc[j][i] * g1[c] + b1[c];
            Xs[r * 132 + c] = h > 0.f ? h : 0.f;
        }
    __syncthreads();

    float a2[10];
#pragma unroll
    for (int c = 0; c < 10; ++c) a2[c] = 0.f;
    for (int kk = 0; kk < 32; ++kk) {
        int k = kk * 4 + p;
        float hv = Xs[r * 132 + k];
#pragma unroll
        for (int c = 0; c < 10; ++c) a2[c] += hv * W2s[k * 10 + c];
    }
#pragma unroll
    for (int c = 0; c < 10; ++c) {
        a2[c] += __shfl_xor(a2[c], 1);
        a2[c] += __shfl_xor(a2[c], 2);
    }
    if (p == 0 && r < mrows) {
        int m = m0 + r;
        float best = -INFINITY;
        int bi = 0;
#pragma unroll
        for (int c = 0; c < 10; ++c) {
            float s = a2[c] + b2[c];
            out_s10[(size_t)m * 10 + c] = s;
            if (s > best) { best = s; bi = c; }
        }
        out_heat[m] = best;
        cls[m] = bi;
    }
}

// ---------------------------------------------------------------------------
// K2: exact top-500 per batch via 64-bit unique keys + MSB radix select +
// bitonic sort of the 500 survivors. One block per batch.
// ---------------------------------------------------------------------------
__device__ __forceinline__ unsigned ordf(float s) {
    unsigned u = __float_as_uint(s);
    return (u & 0x80000000u) ? ~u : (u | 0x80000000u);
}

__global__ void topk_kernel(
    const float* __restrict__ heat,
    const int* __restrict__ cls,
    const int* __restrict__ fcoords,   // (B,NF,2)
    float* __restrict__ out1,          // key_voxel_indices
    float* __restrict__ out4,          // key_class
    int* __restrict__ tki,
    float* __restrict__ keyworld,
    unsigned long long* __restrict__ keys)
{
    const int b = blockIdx.x;
    const int tid = threadIdx.x;
    __shared__ unsigned bins[256];
    __shared__ unsigned long long pref_s;
    __shared__ int k_s;
    __shared__ unsigned cnt_s;
    __shared__ unsigned long long list[512];

    const float* hb = heat + (size_t)b * NF;
    unsigned long long* kb = keys + (size_t)b * NF;
    for (int i = tid; i < NF; i += 1024) {
        float s = hb[i];
        float sig = 1.0f / (1.0f + expf(-s));
        kb[i] = ((unsigned long long)ordf(sig) << 32) | (unsigned)(~(unsigned)i);
    }
    if (tid == 0) { pref_s = 0ull; k_s = NK; }
    __syncthreads();

    for (int d = 7; d >= 0; --d) {
        for (int i2 = tid; i2 < 256; i2 += 1024) bins[i2] = 0u;
        __syncthreads();
        unsigned long long pref = pref_s;
        int shift = (d + 1) * 8;
        unsigned long long hmask = (shift >= 64) ? 0ull : (~0ull << shift);
        for (int i = tid; i < NF; i += 1024) {
            unsigned long long key = kb[i];
            if ((key & hmask) == pref)
                atomicAdd(&bins[(unsigned)(key >> (d * 8)) & 255u], 1u);
        }
        __syncthreads();
        if (tid == 0) {
            int k = k_s;
            int cum = 0;
            for (int c = 255; c >= 0; --c) {
                int nc = cum + (int)bins[c];
                if (nc >= k) {
                    pref_s = pref | ((unsigned long long)(unsigned)c << (d * 8));
                    k_s = k - cum;
                    break;
                }
                cum = nc;
            }
        }
        __syncthreads();
    }
    unsigned long long T = pref_s;  // exact 500th-largest key
    if (tid == 0) cnt_s = 0u;
    __syncthreads();
    for (int i = tid; i < NF; i += 1024) {
        unsigned long long key = kb[i];
        if (key >= T) {
            unsigned pos = atomicAdd(&cnt_s, 1u);
            if (pos < 512u) list[pos] = key;
        }
    }
    __syncthreads();
    int cc = (int)cnt_s;
    for (int i = tid; i < 512; i += 1024)
        if (i >= cc) list[i] = 0ull;
    __syncthreads();
    // bitonic sort, descending (all real keys have bit63 set -> pads last)
    for (int kk = 2; kk <= 512; kk <<= 1) {
        for (int j = kk >> 1; j > 0; j >>= 1) {
            for (int i = tid; i < 512; i += 1024) {
                int ixj = i ^ j;
                if (ixj > i) {
                    unsigned long long a = list[i], bv = list[ixj];
                    bool up = ((i & kk) == 0);
                    bool sw = up ? (a < bv) : (a > bv);
                    if (sw) { list[i] = bv; list[ixj] = a; }
                }
            }
            __syncthreads();
        }
    }
    if (tid < NK) {
        unsigned long long key = list[tid];
        int idx = (int)(~(unsigned)(key & 0xFFFFFFFFull));
        tki[b * NK + tid] = idx;
        int c0 = fcoords[((size_t)b * NF + idx) * 2 + 0];
        int c1 = fcoords[((size_t)b * NF + idx) * 2 + 1];
        size_t o = (size_t)(b * NK + tid);
        out1[o * 3 + 0] = (float)b;
        out1[o * 3 + 1] = (float)c0;
        out1[o * 3 + 2] = (float)c1;
        float wx = __fadd_rn(__fmul_rn(__fmul_rn(__fadd_rn((float)c0, 0.5f), 8.0f), 0.075f), -54.0f);
        float wy = __fadd_rn(__fmul_rn(__fmul_rn(__fadd_rn((float)c1, 0.5f), 8.0f), 0.075f), -54.0f);
        keyworld[o * 2 + 0] = wx;
        keyworld[o * 2 + 1] = wy;
        out4[o] = (float)cls[(size_t)b * NF + idx];
    }
}

// ---------------------------------------------------------------------------
// K3: radius-KNN + 16-neighbor weighted feature sum. One block per (b, key).
// Exact (d2 asc, idx asc) ordering via 64-bit keys, matching top_k(-d2) ties.
// ---------------------------------------------------------------------------
__global__ __launch_bounds__(256) void knn_kernel(
    const float* __restrict__ sfeat,   // (B,NS,128)
    const int* __restrict__ scoords,   // (B,NS,2)
    const float* __restrict__ knn_w,   // (2,16)
    const float* __restrict__ knn_b,   // (2,)
    const float* __restrict__ keyworld,
    float* __restrict__ mf,            // ws: (2,B,NK,128)
    int s, float stride, float r2)
{
    __shared__ unsigned long long list[2048];
    __shared__ unsigned cnt_s;
    const int tid = threadIdx.x;
    const int b = blockIdx.x / NK;
    const int r = blockIdx.x % NK;
    if (tid == 0) cnt_s = 0u;
    __syncthreads();
    const float kx = keyworld[((size_t)b * NK + r) * 2 + 0];
    const float ky = keyworld[((size_t)b * NK + r) * 2 + 1];
    const int2* sc = ((const int2*)scoords) + (size_t)b * NS;
    for (int i = tid; i < NS; i += 256) {
        int2 c = sc[i];
        float sx = __fadd_rn(__fmul_rn(__fmul_rn(__fadd_rn((float)c.x, 0.5f), stride), 0.075f), -54.0f);
        float sy = __fadd_rn(__fmul_rn(__fmul_rn(__fadd_rn((float)c.y, 0.5f), stride), 0.075f), -54.0f);
        float dx = __fsub_rn(kx, sx);
        float dy = __fsub_rn(ky, sy);
        float d2 = __fadd_rn(__fmul_rn(dx, dx), __fmul_rn(dy, dy));
        if (d2 <= r2) {
            unsigned pos = atomicAdd(&cnt_s, 1u);
            if (pos < 2048u)
                list[pos] = ((unsigned long long)__float_as_uint(d2) << 32) | (unsigned)i;
        }
    }
    __syncthreads();
    int cc = (int)cnt_s;
    if (cc > 2048) cc = 2048;
    int n2 = 16;
    while (n2 < cc) n2 <<= 1;
    for (int i = tid; i < n2; i += 256)
        if (i >= cc) list[i] = ~0ull;
    __syncthreads();
    // bitonic ascending over n2 (d2 nonneg -> raw float bits are monotone)
    for (int kk = 2; kk <= n2; kk <<= 1) {
        for (int j = kk >> 1; j > 0; j >>= 1) {
            for (int i = tid; i < n2; i += 256) {
                int ixj = i ^ j;
                if (ixj > i) {
                    unsigned long long a = list[i], bv = list[ixj];
                    bool up = ((i & kk) == 0);
                    bool sw = up ? (a > bv) : (a < bv);
                    if (sw) { list[i] = bv; list[ixj] = a; }
                }
            }
            __syncthreads();
        }
    }
    if (tid < CH) {
        float acc = knn_b[s];
        int K = cc < KNN ? cc : KNN;
        for (int k = 0; k < K; ++k) {
            unsigned i = (unsigned)(list[k] & 0xFFFFFFFFull);
            acc += knn_w[s * 16 + k] * sfeat[((size_t)b * NS + i) * CH + tid];
        }
        mf[(((size_t)s * BB + b) * NK + r) * CH + tid] = acc;
    }
}

// ---------------------------------------------------------------------------
// K4: per-key weight MLP + softmax + cumulative fusion + fuse MLP.
// One block (256 threads) per key.
// ---------------------------------------------------------------------------
__global__ __launch_bounds__(256) void fuse_kernel(
    const float* __restrict__ ffeat,   // (B,NF,128)
    const int* __restrict__ tki,
    const float* __restrict__ kw_w1, const float* __restrict__ kw_g1,
    const float* __restrict__ kw_b1, const float* __restrict__ kw_w2,
    const float* __restrict__ kw_b2,
    const float* __restrict__ fuse_w1, const float* __restrict__ fuse_g1,
    const float* __restrict__ fuse_b1, const float* __restrict__ fuse_w2,
    const float* __restrict__ fuse_b2,
    const float* __restrict__ mf,      // ws: (2,B,NK,128)
    float* __restrict__ out0)
{
    __shared__ float xs[128];
    __shared__ float hs[64];
    __shared__ float l3[3];
    __shared__ float wsm[2];
    __shared__ float fusedv[256];
    __shared__ float h2s[256];
    const int tid = threadIdx.x;
    const int b = blockIdx.x / NK;
    const int r = blockIdx.x % NK;
    int idx = tki[b * NK + r];
    const float* xg = ffeat + ((size_t)b * NF + idx) * CH;
    if (tid < 128) xs[tid] = xg[tid];
    __syncthreads();
    if (tid < 64) {
        float h = 0.f;
        for (int k = 0; k < 128; ++k) h += xs[k] * kw_w1[k * 64 + tid];
        h = h * kw_g1[tid] + kw_b1[tid];
        hs[tid] = h > 0.f ? h : 0.f;
    }
    __syncthreads();
    if (tid < 3) {
        float l = 0.f;
        for (int k = 0; k < 64; ++k) l += hs[k] * kw_w2[k * 3 + tid];
        l3[tid] = l + kw_b2[tid];
    }
    __syncthreads();
    if (tid == 0) {
        float m = fmaxf(l3[0], fmaxf(l3[1], l3[2]));
        float e0 = expf(l3[0] - m), e1 = expf(l3[1] - m), e2 = expf(l3[2] - m);
        float sum = e0 + e1 + e2;
        wsm[0] = e0 / sum;
        wsm[1] = e1 / sum;
    }
    __syncthreads();
    if (tid < 128) {
        size_t o = ((size_t)b * NK + r) * CH + tid;
        float m0 = mf[(((size_t)0 * BB + b) * NK + r) * CH + tid];
        float m1 = mf[(((size_t)1 * BB + b) * NK + r) * CH + tid];
        float kv = wsm[0] * xs[tid];
        float fs = kv * m0;
        float kv2 = wsm[1] * kv;
        fs += kv2 * m1;
        fusedv[tid] = fs;
        fusedv[128 + tid] = kv2;
        (void)o;
    }
    __syncthreads();
    {
        float h2 = 0.f;
        for (int k = 0; k < 256; ++k) h2 += fusedv[k] * fuse_w1[k * 256 + tid];
        h2 = h2 * fuse_g1[tid] + fuse_b1[tid];
        h2s[tid] = h2 > 0.f ? h2 : 0.f;
    }
    __syncthreads();
    if (tid < 128) {
        float o = fuse_b2[tid];
        for (int k = 0; k < 256; ++k) o += h2s[k] * fuse_w2[k * 128 + tid];
        out0[((size_t)b * NK + r) * CH + tid] = o;
    }
}

extern "C" void kernel_launch(void* const* d_in, const int* in_sizes, int n_in,
                              void* d_out, int out_size, void* d_ws, size_t ws_size,
                              hipStream_t stream)
{
    const float* fusion_feat = (const float*)d_in[0];
    const float* src_feat_a  = (const float*)d_in[1];
    const float* src_feat_b  = (const float*)d_in[2];
    const float* heat_w1 = (const float*)d_in[3];
    const float* heat_g1 = (const float*)d_in[4];
    const float* heat_b1 = (const float*)d_in[5];
    const float* heat_w2 = (const float*)d_in[6];
    const float* heat_b2 = (const float*)d_in[7];
    const float* knn_w   = (const float*)d_in[8];
    const float* knn_b   = (const float*)d_in[9];
    const float* kw_w1   = (const float*)d_in[10];
    const float* kw_g1   = (const float*)d_in[11];
    const float* kw_b1   = (const float*)d_in[12];
    const float* kw_w2   = (const float*)d_in[13];
    const float* kw_b2   = (const float*)d_in[14];
    const float* fuse_w1 = (const float*)d_in[15];
    const float* fuse_g1 = (const float*)d_in[16];
    const float* fuse_b1 = (const float*)d_in[17];
    const float* fuse_w2 = (const float*)d_in[18];
    const float* fuse_b2 = (const float*)d_in[19];
    const int* fusion_coords = (const int*)d_in[20];
    const int* src_coords_a  = (const int*)d_in[21];
    const int* src_coords_b  = (const int*)d_in[22];

    float* out = (float*)d_out;
    char* ws = (char*)d_ws;
    int* cls = (int*)(ws + WS_CLS);
    int* tki = (int*)(ws + WS_TKI);
    float* keyworld = (float*)(ws + WS_KW);
    float* mf = (float*)(ws + WS_MF);
    unsigned long long* keys = (unsigned long long*)(ws + WS_KEYS);

    heat_kernel<<<(BB * NF + 63) / 64, 256, 0, stream>>>(
        fusion_feat, heat_w1, heat_g1, heat_b1, heat_w2, heat_b2,
        out + OUT2_OFF, out + OUT3_OFF, cls);

    topk_kernel<<<BB, 1024, 0, stream>>>(
        out + OUT2_OFF, cls, fusion_coords,
        out + OUT1_OFF, out + OUT4_OFF, tki, keyworld, keys);

    knn_kernel<<<BB * NK, 256, 0, stream>>>(
        src_feat_a, src_coords_a, knn_w, knn_b, keyworld, mf,
        0, 4.0f, (float)(2.4 * 2.4));
    knn_kernel<<<BB * NK, 256, 0, stream>>>(
        src_feat_b, src_coords_b, knn_w, knn_b, keyworld, mf,
        1, 8.0f, (float)(4.8 * 4.8));

    fuse_kernel<<<BB * NK, 256, 0, stream>>>(
        fusion_feat, tki, kw_w1, kw_g1, kw_b1, kw_w2, kw_b2,
        fuse_w1, fuse_g1, fuse_b1, fuse_w2, fuse_b2, mf, out + OUT0_OFF);
}

// Round 2
// 341.277 us; speedup vs baseline: 1.3882x; 1.3882x over previous
//
#include <hip/hip_runtime.h>
#include <math.h>

#define BB 2
#define NF 20000
#define NS 30000
#define CH 128
#define NK 500
#define KNN 16

// output offsets (floats, concatenated in return order)
#define OUT0_OFF 0           // out          (B*NK*128) = 128000
#define OUT1_OFF 128000      // key_voxel_indices (B*NK*3) = 3000
#define OUT2_OFF 131000      // heat_scores  (B*NF) = 40000
#define OUT3_OFF 171000      // scores10     (B*NF*10) = 400000
#define OUT4_OFF 571000      // key_class    (B*NK) = 1000

// workspace offsets (bytes)
#define WS_CLS   0           // int32  x 40000  (160000 B)
#define WS_TKI   160000      // int32  x 1000   (4000 B)
#define WS_KW    164000      // float  x 2000   (8000 B)
#define WS_MF    172000      // float  x 256000 (1024000 B)
// keys (u64 x 40000 = 320000 B) OVERLAYS the start of WS_MF: keys are dead
// before knn_kernel writes mf (stream-serialized), so this is safe.
#define WS_KEYS  WS_MF

// ---------------------------------------------------------------------------
// K1: heat MLP + key build.  64 rows/block, 256 threads. Thread t: row r=t/4,
// phase p=t%4, cols c = 16j + 4p + {0..3}, j=0..7. X tile in LDS (stride 132
// -> 2-way bank alias, free). w1 read from global via float4 (L1 resident).
// The p==0 thread also emits the 64-bit topk key (ord(sigmoid)<<32 | ~i).
// ---------------------------------------------------------------------------
__device__ __forceinline__ unsigned ordf(float s) {
    unsigned u = __float_as_uint(s);
    return (u & 0x80000000u) ? ~u : (u | 0x80000000u);
}

__global__ __launch_bounds__(256) void heat_kernel(
    const float* __restrict__ x,      // (B*NF, 128)
    const float* __restrict__ w1,     // (128,128)
    const float* __restrict__ g1, const float* __restrict__ b1,
    const float* __restrict__ w2,     // (128,10)
    const float* __restrict__ b2,     // (10)
    float* __restrict__ out_heat,     // (B*NF)
    float* __restrict__ out_s10,      // (B*NF,10)
    int* __restrict__ cls,            // (B*NF)
    unsigned long long* __restrict__ keys)
{
    __shared__ float Xs[64 * 132];
    __shared__ float W2s[128 * 10];
    const int tid = threadIdx.x;
    const int m0 = blockIdx.x * 64;
    const int mrows = min(64, BB * NF - m0);

    for (int v = tid; v < 1280; v += 256) W2s[v] = w2[v];
    {
        const float4* xv = (const float4*)(x + (size_t)m0 * 128);
        for (int v = tid; v < 64 * 32; v += 256) {
            int row = v >> 5, c4 = v & 31;
            float4 val = (row < mrows) ? xv[v] : make_float4(0.f, 0.f, 0.f, 0.f);
            *((float4*)&Xs[row * 132 + c4 * 4]) = val;
        }
    }
    __syncthreads();

    const int r = tid >> 2;
    const int p = tid & 3;
    float acc[8][4];
#pragma unroll
    for (int j = 0; j < 8; ++j)
#pragma unroll
        for (int i = 0; i < 4; ++i) acc[j][i] = 0.f;

    const float* xrow = &Xs[r * 132];
    const float4* w1v = (const float4*)w1;
#pragma unroll 2
    for (int k = 0; k < 128; ++k) {
        float xk = xrow[k];
        const float4* wrow = w1v + k * 32;
#pragma unroll
        for (int j = 0; j < 8; ++j) {
            float4 w = wrow[j * 4 + p];
            acc[j][0] += xk * w.x;
            acc[j][1] += xk * w.y;
            acc[j][2] += xk * w.z;
            acc[j][3] += xk * w.w;
        }
    }
    __syncthreads();
#pragma unroll
    for (int j = 0; j < 8; ++j)
#pragma unroll
        for (int i = 0; i < 4; ++i) {
            int c = j * 16 + p * 4 + i;
            float h = acc[j][i] * g1[c] + b1[c];
            Xs[r * 132 + c] = h > 0.f ? h : 0.f;
        }
    __syncthreads();

    float a2[10];
#pragma unroll
    for (int c = 0; c < 10; ++c) a2[c] = 0.f;
    for (int kk = 0; kk < 32; ++kk) {
        int k = kk * 4 + p;
        float hv = Xs[r * 132 + k];
#pragma unroll
        for (int c = 0; c < 10; ++c) a2[c] += hv * W2s[k * 10 + c];
    }
#pragma unroll
    for (int c = 0; c < 10; ++c) {
        a2[c] += __shfl_xor(a2[c], 1);
        a2[c] += __shfl_xor(a2[c], 2);
    }
    if (p == 0 && r < mrows) {
        int m = m0 + r;
        float best = -INFINITY;
        int bi = 0;
#pragma unroll
        for (int c = 0; c < 10; ++c) {
            float s = a2[c] + b2[c];
            out_s10[(size_t)m * 10 + c] = s;
            if (s > best) { best = s; bi = c; }
        }
        out_heat[m] = best;
        cls[m] = bi;
        int b = m / NF;
        unsigned i = (unsigned)(m - b * NF);
        float sig = 1.0f / (1.0f + expf(-best));
        keys[m] = ((unsigned long long)ordf(sig) << 32) | (unsigned)(~i);
    }
}

// ---------------------------------------------------------------------------
// K2: exact top-500 per batch, single kernel. LDS 14-bit histogram ->
// hierarchical desc scan -> 10-bit refinement histogram -> 24-bit threshold
// -> collect candidates -> bitonic desc sort -> emit exactly NK keys.
// Full 64-bit key ordering gives exact lax.top_k tie semantics.
// ---------------------------------------------------------------------------
#define H1BINS 16384
#define H2BINS 1024

__global__ __launch_bounds__(1024) void topk_kernel(
    const unsigned long long* __restrict__ keys,
    const int* __restrict__ cls,
    const int* __restrict__ fcoords,   // (B,NF,2)
    float* __restrict__ out1,          // key_voxel_indices
    float* __restrict__ out4,          // key_class
    int* __restrict__ tki,
    float* __restrict__ keyworld)
{
    __shared__ unsigned h[H1BINS];               // 64 KB
    __shared__ unsigned long long list[1024];    // 8 KB
    __shared__ unsigned csum[1024];
    __shared__ unsigned ssum[32];
    __shared__ unsigned sel_s, krem_s, cnt_s;
    const int b = blockIdx.x;
    const int tid = threadIdx.x;
    const unsigned long long* kb = keys + (size_t)b * NF;

    // --- level-1 histogram over top 14 bits ---
    for (int i = tid; i < H1BINS; i += 1024) h[i] = 0u;
    __syncthreads();
#pragma unroll 4
    for (int i = tid; i < NF; i += 1024)
        atomicAdd(&h[(unsigned)(kb[i] >> 50)], 1u);
    __syncthreads();
    {
        unsigned s = 0;
        int base = tid * 16;
#pragma unroll
        for (int j = 0; j < 16; ++j) s += h[base + j];
        csum[tid] = s;
    }
    __syncthreads();
    if (tid < 32) {
        unsigned s = 0;
        for (int j = 0; j < 32; ++j) s += csum[tid * 32 + j];
        ssum[tid] = s;
    }
    __syncthreads();
    if (tid == 0) {
        unsigned K = NK, acc = 0;
        int sidx = 31;
        for (; sidx > 0; --sidx) { if (acc + ssum[sidx] >= K) break; acc += ssum[sidx]; }
        int cidx = sidx * 32 + 31;
        for (;; --cidx) { if (acc + csum[cidx] >= K) break; acc += csum[cidx]; }
        int bin = cidx * 16 + 15;
        for (;; --bin) { if (acc + h[bin] >= K) break; acc += h[bin]; }
        sel_s = (unsigned)bin;
        krem_s = K - acc;     // rank remaining within boundary bin, >=1
    }
    __syncthreads();
    const unsigned T1 = sel_s;
    const unsigned K2 = krem_s;

    // --- level-2 histogram (next 10 bits) within bin T1 ---
    for (int i = tid; i < H2BINS; i += 1024) h[i] = 0u;
    __syncthreads();
#pragma unroll 4
    for (int i = tid; i < NF; i += 1024) {
        unsigned long long key = kb[i];
        if ((unsigned)(key >> 50) == T1)
            atomicAdd(&h[(unsigned)(key >> 40) & 1023u], 1u);
    }
    __syncthreads();
    if (tid < 32) {
        unsigned s = 0;
        for (int j = 0; j < 32; ++j) s += h[tid * 32 + j];
        csum[tid] = s;
    }
    __syncthreads();
    if (tid == 0) {
        unsigned acc = 0;
        int cidx = 31;
        for (; cidx > 0; --cidx) { if (acc + csum[cidx] >= K2) break; acc += csum[cidx]; }
        int bin = cidx * 32 + 31;
        for (;; --bin) { if (acc + h[bin] >= K2) break; acc += h[bin]; }
        sel_s = (T1 << 10) | (unsigned)bin;  // exact 24-bit threshold
        cnt_s = 0u;
    }
    __syncthreads();
    const unsigned thr24 = sel_s;

    // --- collect candidates (top24 >= thr24): <= 499 + boundary sub-bin ---
#pragma unroll 4
    for (int i = tid; i < NF; i += 1024) {
        unsigned long long key = kb[i];
        if ((unsigned)(key >> 40) >= thr24) {
            unsigned pos = atomicAdd(&cnt_s, 1u);
            if (pos < 1024u) list[pos] = key;
        }
    }
    __syncthreads();
    unsigned cc = cnt_s > 1024u ? 1024u : cnt_s;
    if ((unsigned)tid >= cc) list[tid] = 0ull;  // pads sort below real keys
    __syncthreads();

    // --- bitonic sort desc, 1024 elements, 1024 threads ---
    for (int kk = 2; kk <= 1024; kk <<= 1) {
        for (int j = kk >> 1; j > 0; j >>= 1) {
            int i = tid, ixj = i ^ j;
            if (ixj > i) {
                unsigned long long a = list[i], bv = list[ixj];
                bool up = ((i & kk) == 0);
                if (up ? (a < bv) : (a > bv)) { list[i] = bv; list[ixj] = a; }
            }
            __syncthreads();
        }
    }

    if (tid < NK) {
        unsigned long long key = list[tid];
        int idx = (int)(~(unsigned)(key & 0xFFFFFFFFull));
        tki[b * NK + tid] = idx;
        int c0 = fcoords[((size_t)b * NF + idx) * 2 + 0];
        int c1 = fcoords[((size_t)b * NF + idx) * 2 + 1];
        size_t o = (size_t)(b * NK + tid);
        out1[o * 3 + 0] = (float)b;
        out1[o * 3 + 1] = (float)c0;
        out1[o * 3 + 2] = (float)c1;
        float wx = __fadd_rn(__fmul_rn(__fmul_rn(__fadd_rn((float)c0, 0.5f), 8.0f), 0.075f), -54.0f);
        float wy = __fadd_rn(__fmul_rn(__fmul_rn(__fadd_rn((float)c1, 0.5f), 8.0f), 0.075f), -54.0f);
        keyworld[o * 2 + 0] = wx;
        keyworld[o * 2 + 1] = wy;
        out4[o] = (float)cls[(size_t)b * NF + idx];
    }
}

// ---------------------------------------------------------------------------
// K3: radius-KNN + 16-neighbor weighted feature sum, BOTH sources in one
// launch (2*B*NK blocks). Exact (d2 asc, idx asc) ordering via 64-bit keys.
// ---------------------------------------------------------------------------
__global__ __launch_bounds__(256) void knn_kernel(
    const float* __restrict__ sfa, const int* __restrict__ sca,
    const float* __restrict__ sfb, const int* __restrict__ scb,
    const float* __restrict__ knn_w,   // (2,16)
    const float* __restrict__ knn_b,   // (2,)
    const float* __restrict__ keyworld,
    float* __restrict__ mf)            // ws: (2,B,NK,128)
{
    __shared__ unsigned long long list[2048];
    __shared__ unsigned cnt_s;
    const int tid = threadIdx.x;
    const int blk = blockIdx.x;
    const int s = blk / (BB * NK);
    const int rest = blk % (BB * NK);
    const int b = rest / NK;
    const int r = rest % NK;
    const float* sfeat = s ? sfb : sfa;
    const int2* sc = ((const int2*)(s ? scb : sca)) + (size_t)b * NS;
    const float stride = s ? 8.0f : 4.0f;
    const float r2 = s ? (float)(4.8 * 4.8) : (float)(2.4 * 2.4);

    if (tid == 0) cnt_s = 0u;
    __syncthreads();
    const float kx = keyworld[((size_t)b * NK + r) * 2 + 0];
    const float ky = keyworld[((size_t)b * NK + r) * 2 + 1];
    for (int i = tid; i < NS; i += 256) {
        int2 c = sc[i];
        float sx = __fadd_rn(__fmul_rn(__fmul_rn(__fadd_rn((float)c.x, 0.5f), stride), 0.075f), -54.0f);
        float sy = __fadd_rn(__fmul_rn(__fmul_rn(__fadd_rn((float)c.y, 0.5f), stride), 0.075f), -54.0f);
        float dx = __fsub_rn(kx, sx);
        float dy = __fsub_rn(ky, sy);
        float d2 = __fadd_rn(__fmul_rn(dx, dx), __fmul_rn(dy, dy));
        if (d2 <= r2) {
            unsigned pos = atomicAdd(&cnt_s, 1u);
            if (pos < 2048u)
                list[pos] = ((unsigned long long)__float_as_uint(d2) << 32) | (unsigned)i;
        }
    }
    __syncthreads();
    int cc = (int)cnt_s;
    if (cc > 2048) cc = 2048;
    int n2 = 16;
    while (n2 < cc) n2 <<= 1;
    for (int i = tid; i < n2; i += 256)
        if (i >= cc) list[i] = ~0ull;
    __syncthreads();
    for (int kk = 2; kk <= n2; kk <<= 1) {
        for (int j = kk >> 1; j > 0; j >>= 1) {
            for (int i = tid; i < n2; i += 256) {
                int ixj = i ^ j;
                if (ixj > i) {
                    unsigned long long a = list[i], bv = list[ixj];
                    bool up = ((i & kk) == 0);
                    bool sw = up ? (a > bv) : (a < bv);
                    if (sw) { list[i] = bv; list[ixj] = a; }
                }
            }
            __syncthreads();
        }
    }
    if (tid < CH) {
        float acc = knn_b[s];
        int K = cc < KNN ? cc : KNN;
        for (int k = 0; k < K; ++k) {
            unsigned i = (unsigned)(list[k] & 0xFFFFFFFFull);
            acc += knn_w[s * 16 + k] * sfeat[((size_t)b * NS + i) * CH + tid];
        }
        mf[(((size_t)s * BB + b) * NK + r) * CH + tid] = acc;
    }
}

// ---------------------------------------------------------------------------
// K4: per-key weight MLP + softmax + cumulative fusion + fuse MLP.
// One block (256 threads) per key.
// ---------------------------------------------------------------------------
__global__ __launch_bounds__(256) void fuse_kernel(
    const float* __restrict__ ffeat,   // (B,NF,128)
    const int* __restrict__ tki,
    const float* __restrict__ kw_w1, const float* __restrict__ kw_g1,
    const float* __restrict__ kw_b1, const float* __restrict__ kw_w2,
    const float* __restrict__ kw_b2,
    const float* __restrict__ fuse_w1, const float* __restrict__ fuse_g1,
    const float* __restrict__ fuse_b1, const float* __restrict__ fuse_w2,
    const float* __restrict__ fuse_b2,
    const float* __restrict__ mf,      // ws: (2,B,NK,128)
    float* __restrict__ out0)
{
    __shared__ float xs[128];
    __shared__ float hs[64];
    __shared__ float l3[3];
    __shared__ float wsm[2];
    __shared__ float fusedv[256];
    __shared__ float h2s[256];
    const int tid = threadIdx.x;
    const int b = blockIdx.x / NK;
    const int r = blockIdx.x % NK;
    int idx = tki[b * NK + r];
    const float* xg = ffeat + ((size_t)b * NF + idx) * CH;
    if (tid < 128) xs[tid] = xg[tid];
    __syncthreads();
    if (tid < 64) {
        float h = 0.f;
        for (int k = 0; k < 128; ++k) h += xs[k] * kw_w1[k * 64 + tid];
        h = h * kw_g1[tid] + kw_b1[tid];
        hs[tid] = h > 0.f ? h : 0.f;
    }
    __syncthreads();
    if (tid < 3) {
        float l = 0.f;
        for (int k = 0; k < 64; ++k) l += hs[k] * kw_w2[k * 3 + tid];
        l3[tid] = l + kw_b2[tid];
    }
    __syncthreads();
    if (tid == 0) {
        float m = fmaxf(l3[0], fmaxf(l3[1], l3[2]));
        float e0 = expf(l3[0] - m), e1 = expf(l3[1] - m), e2 = expf(l3[2] - m);
        float sum = e0 + e1 + e2;
        wsm[0] = e0 / sum;
        wsm[1] = e1 / sum;
    }
    __syncthreads();
    if (tid < 128) {
        float m0 = mf[(((size_t)0 * BB + b) * NK + r) * CH + tid];
        float m1 = mf[(((size_t)1 * BB + b) * NK + r) * CH + tid];
        float kv = wsm[0] * xs[tid];
        float fs = kv * m0;
        float kv2 = wsm[1] * kv;
        fs += kv2 * m1;
        fusedv[tid] = fs;
        fusedv[128 + tid] = kv2;
    }
    __syncthreads();
    {
        float h2 = 0.f;
        for (int k = 0; k < 256; ++k) h2 += fusedv[k] * fuse_w1[k * 256 + tid];
        h2 = h2 * fuse_g1[tid] + fuse_b1[tid];
        h2s[tid] = h2 > 0.f ? h2 : 0.f;
    }
    __syncthreads();
    if (tid < 128) {
        float o = fuse_b2[tid];
        for (int k = 0; k < 256; ++k) o += h2s[k] * fuse_w2[k * 128 + tid];
        out0[((size_t)b * NK + r) * CH + tid] = o;
    }
}

extern "C" void kernel_launch(void* const* d_in, const int* in_sizes, int n_in,
                              void* d_out, int out_size, void* d_ws, size_t ws_size,
                              hipStream_t stream)
{
    const float* fusion_feat = (const float*)d_in[0];
    const float* src_feat_a  = (const float*)d_in[1];
    const float* src_feat_b  = (const float*)d_in[2];
    const float* heat_w1 = (const float*)d_in[3];
    const float* heat_g1 = (const float*)d_in[4];
    const float* heat_b1 = (const float*)d_in[5];
    const float* heat_w2 = (const float*)d_in[6];
    const float* heat_b2 = (const float*)d_in[7];
    const float* knn_w   = (const float*)d_in[8];
    const float* knn_b   = (const float*)d_in[9];
    const float* kw_w1   = (const float*)d_in[10];
    const float* kw_g1   = (const float*)d_in[11];
    const float* kw_b1   = (const float*)d_in[12];
    const float* kw_w2   = (const float*)d_in[13];
    const float* kw_b2   = (const float*)d_in[14];
    const float* fuse_w1 = (const float*)d_in[15];
    const float* fuse_g1 = (const float*)d_in[16];
    const float* fuse_b1 = (const float*)d_in[17];
    const float* fuse_w2 = (const float*)d_in[18];
    const float* fuse_b2 = (const float*)d_in[19];
    const int* fusion_coords = (const int*)d_in[20];
    const int* src_coords_a  = (const int*)d_in[21];
    const int* src_coords_b  = (const int*)d_in[22];

    float* out = (float*)d_out;
    char* ws = (char*)d_ws;
    int* cls = (int*)(ws + WS_CLS);
    int* tki = (int*)(ws + WS_TKI);
    float* keyworld = (float*)(ws + WS_KW);
    float* mf = (float*)(ws + WS_MF);
    unsigned long long* keys = (unsigned long long*)(ws + WS_KEYS);

    heat_kernel<<<(BB * NF + 63) / 64, 256, 0, stream>>>(
        fusion_feat, heat_w1, heat_g1, heat_b1, heat_w2, heat_b2,
        out + OUT2_OFF, out + OUT3_OFF, cls, keys);

    topk_kernel<<<BB, 1024, 0, stream>>>(
        keys, cls, fusion_coords,
        out + OUT1_OFF, out + OUT4_OFF, tki, keyworld);

    knn_kernel<<<2 * BB * NK, 256, 0, stream>>>(
        src_feat_a, src_coords_a, src_feat_b, src_coords_b,
        knn_w, knn_b, keyworld, mf);

    fuse_kernel<<<BB * NK, 256, 0, stream>>>(
        fusion_feat, tki, kw_w1, kw_g1, kw_b1, kw_w2, kw_b2,
        fuse_w1, fuse_g1, fuse_b1, fuse_w2, fuse_b2, mf, out + OUT0_OFF);
}

// Round 3
// 284.285 us; speedup vs baseline: 1.6665x; 1.2005x over previous
//
#include <hip/hip_runtime.h>
#include <math.h>

#define BB 2
#define NF 20000
#define NS 30000
#define CH 128
#define NK 500
#define KNN 16
#define KPB 4

// output offsets (floats, concatenated in return order)
#define OUT0_OFF 0           // out          (B*NK*128) = 128000
#define OUT1_OFF 128000      // key_voxel_indices (B*NK*3) = 3000
#define OUT2_OFF 131000      // heat_scores  (B*NF) = 40000
#define OUT3_OFF 171000      // scores10     (B*NF*10) = 400000
#define OUT4_OFF 571000      // key_class    (B*NK) = 1000

// workspace offsets (bytes)
#define WS_CLS   0           // int32  x 40000  (160000 B)
#define WS_TKI   160000      // int32  x 1000   (4000 B)
#define WS_KW    164000      // float  x 2000   (8000 B)
#define WS_MF    172000      // float  x 256000 (1024000 B)
// keys (u64 x 40000 = 320000 B) OVERLAYS the start of WS_MF: keys are dead
// before knn_kernel writes mf (stream-serialized), so this is safe.
#define WS_KEYS  WS_MF

__device__ __forceinline__ unsigned ordf(float s) {
    unsigned u = __float_as_uint(s);
    return (u & 0x80000000u) ? ~u : (u | 0x80000000u);
}

// ---------------------------------------------------------------------------
// K1: heat MLP, LDS-tiled SGEMM. 625 blocks x 256 thr; tile M=64 x N=128,
// K chunked by 64. Thread (tx=tid&15, ty=tid>>4) owns 4 rows x 8 cols.
// As[row][k] stride 72 (bank-spread), Ws[k][col] stride 132. Layer-2 H tile
// aliases Ws. w1 global traffic: 64 KB/block (was 4 MB/block).
// ---------------------------------------------------------------------------
__global__ __launch_bounds__(256) void heat_kernel(
    const float* __restrict__ x,      // (B*NF, 128)
    const float* __restrict__ w1,     // (128,128)
    const float* __restrict__ g1, const float* __restrict__ b1,
    const float* __restrict__ w2,     // (128,10)
    const float* __restrict__ b2,     // (10)
    float* __restrict__ out_heat,     // (B*NF)
    float* __restrict__ out_s10,      // (B*NF,10)
    int* __restrict__ cls,            // (B*NF)
    unsigned long long* __restrict__ keys)
{
    __shared__ float As[64 * 72];     // 18.4 KB  [row][k-chunk]
    __shared__ float Ws[64 * 132];    // 33.8 KB  [k-chunk][col]; aliased as H
    __shared__ float W2s[1280];       // 5 KB
    const int tid = threadIdx.x;
    const int m0 = blockIdx.x * 64;   // 625*64 == 40000 exactly
    const int tx = tid & 15;
    const int ty = tid >> 4;

    for (int v = tid; v < 1280; v += 256) W2s[v] = w2[v];

    float acc[4][8];
#pragma unroll
    for (int i = 0; i < 4; ++i)
#pragma unroll
        for (int j = 0; j < 8; ++j) acc[i][j] = 0.f;

    const float4* xv = (const float4*)x;
    const float4* w1v = (const float4*)w1;

    for (int kc = 0; kc < 128; kc += 64) {
        // stage As: 64 rows x 64 k = 1024 float4, 4/thread
#pragma unroll
        for (int i = 0; i < 4; ++i) {
            int v = tid + i * 256;
            int row = v >> 4, c4 = v & 15;
            float4 val = xv[(size_t)(m0 + row) * 32 + (kc >> 2) + c4];
            *(float4*)&As[row * 72 + c4 * 4] = val;
        }
        // stage Ws: 64 k x 128 cols = 2048 float4, 8/thread
#pragma unroll
        for (int i = 0; i < 8; ++i) {
            int v = tid + i * 256;
            int k = v >> 5, c4 = v & 31;
            float4 val = w1v[(size_t)(kc + k) * 32 + c4];
            *(float4*)&Ws[k * 132 + c4 * 4] = val;
        }
        __syncthreads();

        const float* a0p = &As[(ty * 4 + 0) * 72];
        const float* a1p = &As[(ty * 4 + 1) * 72];
        const float* a2p = &As[(ty * 4 + 2) * 72];
        const float* a3p = &As[(ty * 4 + 3) * 72];
#pragma unroll 4
        for (int k = 0; k < 64; ++k) {
            float4 bA = *(const float4*)&Ws[k * 132 + tx * 8];
            float4 bB = *(const float4*)&Ws[k * 132 + tx * 8 + 4];
            float a0 = a0p[k], a1 = a1p[k], a2 = a2p[k], a3 = a3p[k];
            acc[0][0] += a0 * bA.x; acc[0][1] += a0 * bA.y; acc[0][2] += a0 * bA.z; acc[0][3] += a0 * bA.w;
            acc[0][4] += a0 * bB.x; acc[0][5] += a0 * bB.y; acc[0][6] += a0 * bB.z; acc[0][7] += a0 * bB.w;
            acc[1][0] += a1 * bA.x; acc[1][1] += a1 * bA.y; acc[1][2] += a1 * bA.z; acc[1][3] += a1 * bA.w;
            acc[1][4] += a1 * bB.x; acc[1][5] += a1 * bB.y; acc[1][6] += a1 * bB.z; acc[1][7] += a1 * bB.w;
            acc[2][0] += a2 * bA.x; acc[2][1] += a2 * bA.y; acc[2][2] += a2 * bA.z; acc[2][3] += a2 * bA.w;
            acc[2][4] += a2 * bB.x; acc[2][5] += a2 * bB.y; acc[2][6] += a2 * bB.z; acc[2][7] += a2 * bB.w;
            acc[3][0] += a3 * bA.x; acc[3][1] += a3 * bA.y; acc[3][2] += a3 * bA.z; acc[3][3] += a3 * bA.w;
            acc[3][4] += a3 * bB.x; acc[3][5] += a3 * bB.y; acc[3][6] += a3 * bB.z; acc[3][7] += a3 * bB.w;
        }
        __syncthreads();
    }

    // epilogue layer 1: h = relu(acc*g1+b1) -> H tile (aliases Ws, stride 132)
    float4 g1a = ((const float4*)g1)[tx * 2], g1b = ((const float4*)g1)[tx * 2 + 1];
    float4 b1a = ((const float4*)b1)[tx * 2], b1b = ((const float4*)b1)[tx * 2 + 1];
    float* Hs = Ws;
#pragma unroll
    for (int i = 0; i < 4; ++i) {
        int row = ty * 4 + i;
        float4 hA, hB;
        hA.x = fmaxf(acc[i][0] * g1a.x + b1a.x, 0.f);
        hA.y = fmaxf(acc[i][1] * g1a.y + b1a.y, 0.f);
        hA.z = fmaxf(acc[i][2] * g1a.z + b1a.z, 0.f);
        hA.w = fmaxf(acc[i][3] * g1a.w + b1a.w, 0.f);
        hB.x = fmaxf(acc[i][4] * g1b.x + b1b.x, 0.f);
        hB.y = fmaxf(acc[i][5] * g1b.y + b1b.y, 0.f);
        hB.z = fmaxf(acc[i][6] * g1b.z + b1b.z, 0.f);
        hB.w = fmaxf(acc[i][7] * g1b.w + b1b.w, 0.f);
        *(float4*)&Hs[row * 132 + tx * 8] = hA;
        *(float4*)&Hs[row * 132 + tx * 8 + 4] = hB;
    }
    __syncthreads();

    // layer 2: 4 threads/row (p=tid&3), 10 cols
    const int r = tid >> 2;
    const int p = tid & 3;
    float a2[10];
#pragma unroll
    for (int c = 0; c < 10; ++c) a2[c] = 0.f;
    for (int kk = 0; kk < 32; ++kk) {
        int k = kk * 4 + p;
        float hv = Hs[r * 132 + k];
#pragma unroll
        for (int c = 0; c < 10; ++c) a2[c] += hv * W2s[k * 10 + c];
    }
#pragma unroll
    for (int c = 0; c < 10; ++c) {
        a2[c] += __shfl_xor(a2[c], 1);
        a2[c] += __shfl_xor(a2[c], 2);
    }
    if (p == 0) {
        int m = m0 + r;
        float best = -INFINITY;
        int bi = 0;
#pragma unroll
        for (int c = 0; c < 10; ++c) {
            float s = a2[c] + b2[c];
            out_s10[(size_t)m * 10 + c] = s;
            if (s > best) { best = s; bi = c; }
        }
        out_heat[m] = best;
        cls[m] = bi;
        int b = m / NF;
        unsigned i = (unsigned)(m - b * NF);
        float sig = 1.0f / (1.0f + expf(-best));
        keys[m] = ((unsigned long long)ordf(sig) << 32) | (unsigned)(~i);
    }
}

// ---------------------------------------------------------------------------
// K2: exact top-500 per batch, single kernel (unchanged from R2).
// ---------------------------------------------------------------------------
#define H1BINS 16384
#define H2BINS 1024

__global__ __launch_bounds__(1024) void topk_kernel(
    const unsigned long long* __restrict__ keys,
    const int* __restrict__ cls,
    const int* __restrict__ fcoords,
    float* __restrict__ out1,
    float* __restrict__ out4,
    int* __restrict__ tki,
    float* __restrict__ keyworld)
{
    __shared__ unsigned h[H1BINS];
    __shared__ unsigned long long list[1024];
    __shared__ unsigned csum[1024];
    __shared__ unsigned ssum[32];
    __shared__ unsigned sel_s, krem_s, cnt_s;
    const int b = blockIdx.x;
    const int tid = threadIdx.x;
    const unsigned long long* kb = keys + (size_t)b * NF;

    for (int i = tid; i < H1BINS; i += 1024) h[i] = 0u;
    __syncthreads();
#pragma unroll 4
    for (int i = tid; i < NF; i += 1024)
        atomicAdd(&h[(unsigned)(kb[i] >> 50)], 1u);
    __syncthreads();
    {
        unsigned s = 0;
        int base = tid * 16;
#pragma unroll
        for (int j = 0; j < 16; ++j) s += h[base + j];
        csum[tid] = s;
    }
    __syncthreads();
    if (tid < 32) {
        unsigned s = 0;
        for (int j = 0; j < 32; ++j) s += csum[tid * 32 + j];
        ssum[tid] = s;
    }
    __syncthreads();
    if (tid == 0) {
        unsigned K = NK, acc = 0;
        int sidx = 31;
        for (; sidx > 0; --sidx) { if (acc + ssum[sidx] >= K) break; acc += ssum[sidx]; }
        int cidx = sidx * 32 + 31;
        for (;; --cidx) { if (acc + csum[cidx] >= K) break; acc += csum[cidx]; }
        int bin = cidx * 16 + 15;
        for (;; --bin) { if (acc + h[bin] >= K) break; acc += h[bin]; }
        sel_s = (unsigned)bin;
        krem_s = K - acc;
    }
    __syncthreads();
    const unsigned T1 = sel_s;
    const unsigned K2 = krem_s;

    for (int i = tid; i < H2BINS; i += 1024) h[i] = 0u;
    __syncthreads();
#pragma unroll 4
    for (int i = tid; i < NF; i += 1024) {
        unsigned long long key = kb[i];
        if ((unsigned)(key >> 50) == T1)
            atomicAdd(&h[(unsigned)(key >> 40) & 1023u], 1u);
    }
    __syncthreads();
    if (tid < 32) {
        unsigned s = 0;
        for (int j = 0; j < 32; ++j) s += h[tid * 32 + j];
        csum[tid] = s;
    }
    __syncthreads();
    if (tid == 0) {
        unsigned acc = 0;
        int cidx = 31;
        for (; cidx > 0; --cidx) { if (acc + csum[cidx] >= K2) break; acc += csum[cidx]; }
        int bin = cidx * 32 + 31;
        for (;; --bin) { if (acc + h[bin] >= K2) break; acc += h[bin]; }
        sel_s = (T1 << 10) | (unsigned)bin;
        cnt_s = 0u;
    }
    __syncthreads();
    const unsigned thr24 = sel_s;

#pragma unroll 4
    for (int i = tid; i < NF; i += 1024) {
        unsigned long long key = kb[i];
        if ((unsigned)(key >> 40) >= thr24) {
            unsigned pos = atomicAdd(&cnt_s, 1u);
            if (pos < 1024u) list[pos] = key;
        }
    }
    __syncthreads();
    unsigned cc = cnt_s > 1024u ? 1024u : cnt_s;
    if ((unsigned)tid >= cc) list[tid] = 0ull;
    __syncthreads();

    for (int kk = 2; kk <= 1024; kk <<= 1) {
        for (int j = kk >> 1; j > 0; j >>= 1) {
            int i = tid, ixj = i ^ j;
            if (ixj > i) {
                unsigned long long a = list[i], bv = list[ixj];
                bool up = ((i & kk) == 0);
                if (up ? (a < bv) : (a > bv)) { list[i] = bv; list[ixj] = a; }
            }
            __syncthreads();
        }
    }

    if (tid < NK) {
        unsigned long long key = list[tid];
        int idx = (int)(~(unsigned)(key & 0xFFFFFFFFull));
        tki[b * NK + tid] = idx;
        int c0 = fcoords[((size_t)b * NF + idx) * 2 + 0];
        int c1 = fcoords[((size_t)b * NF + idx) * 2 + 1];
        size_t o = (size_t)(b * NK + tid);
        out1[o * 3 + 0] = (float)b;
        out1[o * 3 + 1] = (float)c0;
        out1[o * 3 + 2] = (float)c1;
        float wx = __fadd_rn(__fmul_rn(__fmul_rn(__fadd_rn((float)c0, 0.5f), 8.0f), 0.075f), -54.0f);
        float wy = __fadd_rn(__fmul_rn(__fmul_rn(__fadd_rn((float)c1, 0.5f), 8.0f), 0.075f), -54.0f);
        keyworld[o * 2 + 0] = wx;
        keyworld[o * 2 + 1] = wy;
        out4[o] = (float)cls[(size_t)b * NF + idx];
    }
}

// ---------------------------------------------------------------------------
// K3: radius-KNN + 16-neighbor weighted feature sum (unchanged from R2).
// ---------------------------------------------------------------------------
__global__ __launch_bounds__(256) void knn_kernel(
    const float* __restrict__ sfa, const int* __restrict__ sca,
    const float* __restrict__ sfb, const int* __restrict__ scb,
    const float* __restrict__ knn_w,
    const float* __restrict__ knn_b,
    const float* __restrict__ keyworld,
    float* __restrict__ mf)
{
    __shared__ unsigned long long list[2048];
    __shared__ unsigned cnt_s;
    const int tid = threadIdx.x;
    const int blk = blockIdx.x;
    const int s = blk / (BB * NK);
    const int rest = blk % (BB * NK);
    const int b = rest / NK;
    const int r = rest % NK;
    const float* sfeat = s ? sfb : sfa;
    const int2* sc = ((const int2*)(s ? scb : sca)) + (size_t)b * NS;
    const float stride = s ? 8.0f : 4.0f;
    const float r2 = s ? (float)(4.8 * 4.8) : (float)(2.4 * 2.4);

    if (tid == 0) cnt_s = 0u;
    __syncthreads();
    const float kx = keyworld[((size_t)b * NK + r) * 2 + 0];
    const float ky = keyworld[((size_t)b * NK + r) * 2 + 1];
    for (int i = tid; i < NS; i += 256) {
        int2 c = sc[i];
        float sx = __fadd_rn(__fmul_rn(__fmul_rn(__fadd_rn((float)c.x, 0.5f), stride), 0.075f), -54.0f);
        float sy = __fadd_rn(__fmul_rn(__fmul_rn(__fadd_rn((float)c.y, 0.5f), stride), 0.075f), -54.0f);
        float dx = __fsub_rn(kx, sx);
        float dy = __fsub_rn(ky, sy);
        float d2 = __fadd_rn(__fmul_rn(dx, dx), __fmul_rn(dy, dy));
        if (d2 <= r2) {
            unsigned pos = atomicAdd(&cnt_s, 1u);
            if (pos < 2048u)
                list[pos] = ((unsigned long long)__float_as_uint(d2) << 32) | (unsigned)i;
        }
    }
    __syncthreads();
    int cc = (int)cnt_s;
    if (cc > 2048) cc = 2048;
    int n2 = 16;
    while (n2 < cc) n2 <<= 1;
    for (int i = tid; i < n2; i += 256)
        if (i >= cc) list[i] = ~0ull;
    __syncthreads();
    for (int kk = 2; kk <= n2; kk <<= 1) {
        for (int j = kk >> 1; j > 0; j >>= 1) {
            for (int i = tid; i < n2; i += 256) {
                int ixj = i ^ j;
                if (ixj > i) {
                    unsigned long long a = list[i], bv = list[ixj];
                    bool up = ((i & kk) == 0);
                    bool sw = up ? (a > bv) : (a < bv);
                    if (sw) { list[i] = bv; list[ixj] = a; }
                }
            }
            __syncthreads();
        }
    }
    if (tid < CH) {
        float acc = knn_b[s];
        int K = cc < KNN ? cc : KNN;
        for (int k = 0; k < K; ++k) {
            unsigned i = (unsigned)(list[k] & 0xFFFFFFFFull);
            acc += knn_w[s * 16 + k] * sfeat[((size_t)b * NS + i) * CH + tid];
        }
        mf[(((size_t)s * BB + b) * NK + r) * CH + tid] = acc;
    }
}

// ---------------------------------------------------------------------------
// K4: fuse MLP, 4 keys per block (250 blocks): weights read once per 4 keys,
// 4 FMAs per weight load. w1 L2 traffic 400 MB -> 100 MB.
// ---------------------------------------------------------------------------
__global__ __launch_bounds__(256) void fuse_kernel(
    const float* __restrict__ ffeat,
    const int* __restrict__ tki,
    const float* __restrict__ kw_w1, const float* __restrict__ kw_g1,
    const float* __restrict__ kw_b1, const float* __restrict__ kw_w2,
    const float* __restrict__ kw_b2,
    const float* __restrict__ fuse_w1, const float* __restrict__ fuse_g1,
    const float* __restrict__ fuse_b1, const float* __restrict__ fuse_w2,
    const float* __restrict__ fuse_b2,
    const float* __restrict__ mf,
    float* __restrict__ out0)
{
    __shared__ float xs[KPB * 128];
    __shared__ float hsX[KPB * 64];
    __shared__ float l3[KPB * 3];
    __shared__ float wsm[KPB * 2];
    __shared__ float fusedv[KPB * 256];
    __shared__ float h2s[KPB * 256];
    __shared__ int idxs[KPB], bs[KPB], rs[KPB];
    const int tid = threadIdx.x;
    const int f0 = blockIdx.x * KPB;

    if (tid < KPB) {
        int flat = f0 + tid;
        int b = flat / NK;
        bs[tid] = b;
        rs[tid] = flat - b * NK;
        idxs[tid] = tki[flat];
    }
    __syncthreads();
    for (int v = tid; v < KPB * 128; v += 256) {
        int key = v >> 7, c = v & 127;
        xs[v] = ffeat[((size_t)bs[key] * NF + idxs[key]) * CH + c];
    }
    __syncthreads();
    if (tid < 64) {
        float h[KPB] = {0.f, 0.f, 0.f, 0.f};
        for (int k = 0; k < 128; ++k) {
            float wv = kw_w1[k * 64 + tid];
#pragma unroll
            for (int j = 0; j < KPB; ++j) h[j] += xs[j * 128 + k] * wv;
        }
        float g = kw_g1[tid], bb = kw_b1[tid];
#pragma unroll
        for (int j = 0; j < KPB; ++j) {
            float t = h[j] * g + bb;
            hsX[j * 64 + tid] = t > 0.f ? t : 0.f;
        }
    }
    __syncthreads();
    if (tid < KPB * 3) {
        int key = tid / 3, jj = tid - key * 3;
        float l = 0.f;
        for (int k = 0; k < 64; ++k) l += hsX[key * 64 + k] * kw_w2[k * 3 + jj];
        l3[key * 3 + jj] = l + kw_b2[jj];
    }
    __syncthreads();
    if (tid < KPB) {
        float l0 = l3[tid * 3], l1 = l3[tid * 3 + 1], l2 = l3[tid * 3 + 2];
        float m = fmaxf(l0, fmaxf(l1, l2));
        float e0 = expf(l0 - m), e1 = expf(l1 - m), e2 = expf(l2 - m);
        float sum = e0 + e1 + e2;
        wsm[tid * 2 + 0] = e0 / sum;
        wsm[tid * 2 + 1] = e1 / sum;
    }
    __syncthreads();
    for (int v = tid; v < KPB * 256; v += 256) {
        int key = v >> 8, c = v & 255;
        float w0 = wsm[key * 2], w1_ = wsm[key * 2 + 1];
        if (c < 128) {
            int b = bs[key], r = rs[key];
            float xv_ = xs[key * 128 + c];
            float m0 = mf[(((size_t)0 * BB + b) * NK + r) * CH + c];
            float m1 = mf[(((size_t)1 * BB + b) * NK + r) * CH + c];
            float kv = w0 * xv_;
            float fs = kv * m0;
            float kv2 = w1_ * kv;
            fusedv[v] = fs + kv2 * m1;
        } else {
            float xv_ = xs[key * 128 + (c - 128)];
            float kv = w0 * xv_;
            fusedv[v] = w1_ * kv;
        }
    }
    __syncthreads();
    {
        float acc4[KPB] = {0.f, 0.f, 0.f, 0.f};
        for (int k = 0; k < 256; ++k) {
            float wv = fuse_w1[k * 256 + tid];
#pragma unroll
            for (int j = 0; j < KPB; ++j) acc4[j] += fusedv[j * 256 + k] * wv;
        }
        float g = fuse_g1[tid], bb = fuse_b1[tid];
#pragma unroll
        for (int j = 0; j < KPB; ++j) {
            float t = acc4[j] * g + bb;
            h2s[j * 256 + tid] = t > 0.f ? t : 0.f;
        }
    }
    __syncthreads();
    if (tid < 128) {
        float o[KPB];
        float bb = fuse_b2[tid];
#pragma unroll
        for (int j = 0; j < KPB; ++j) o[j] = bb;
        for (int k = 0; k < 256; ++k) {
            float wv = fuse_w2[k * 128 + tid];
#pragma unroll
            for (int j = 0; j < KPB; ++j) o[j] += h2s[j * 256 + k] * wv;
        }
#pragma unroll
        for (int j = 0; j < KPB; ++j)
            out0[((size_t)bs[j] * NK + rs[j]) * CH + tid] = o[j];
    }
}

extern "C" void kernel_launch(void* const* d_in, const int* in_sizes, int n_in,
                              void* d_out, int out_size, void* d_ws, size_t ws_size,
                              hipStream_t stream)
{
    const float* fusion_feat = (const float*)d_in[0];
    const float* src_feat_a  = (const float*)d_in[1];
    const float* src_feat_b  = (const float*)d_in[2];
    const float* heat_w1 = (const float*)d_in[3];
    const float* heat_g1 = (const float*)d_in[4];
    const float* heat_b1 = (const float*)d_in[5];
    const float* heat_w2 = (const float*)d_in[6];
    const float* heat_b2 = (const float*)d_in[7];
    const float* knn_w   = (const float*)d_in[8];
    const float* knn_b   = (const float*)d_in[9];
    const float* kw_w1   = (const float*)d_in[10];
    const float* kw_g1   = (const float*)d_in[11];
    const float* kw_b1   = (const float*)d_in[12];
    const float* kw_w2   = (const float*)d_in[13];
    const float* kw_b2   = (const float*)d_in[14];
    const float* fuse_w1 = (const float*)d_in[15];
    const float* fuse_g1 = (const float*)d_in[16];
    const float* fuse_b1 = (const float*)d_in[17];
    const float* fuse_w2 = (const float*)d_in[18];
    const float* fuse_b2 = (const float*)d_in[19];
    const int* fusion_coords = (const int*)d_in[20];
    const int* src_coords_a  = (const int*)d_in[21];
    const int* src_coords_b  = (const int*)d_in[22];

    float* out = (float*)d_out;
    char* ws = (char*)d_ws;
    int* cls = (int*)(ws + WS_CLS);
    int* tki = (int*)(ws + WS_TKI);
    float* keyworld = (float*)(ws + WS_KW);
    float* mf = (float*)(ws + WS_MF);
    unsigned long long* keys = (unsigned long long*)(ws + WS_KEYS);

    heat_kernel<<<(BB * NF) / 64, 256, 0, stream>>>(
        fusion_feat, heat_w1, heat_g1, heat_b1, heat_w2, heat_b2,
        out + OUT2_OFF, out + OUT3_OFF, cls, keys);

    topk_kernel<<<BB, 1024, 0, stream>>>(
        keys, cls, fusion_coords,
        out + OUT1_OFF, out + OUT4_OFF, tki, keyworld);

    knn_kernel<<<2 * BB * NK, 256, 0, stream>>>(
        src_feat_a, src_coords_a, src_feat_b, src_coords_b,
        knn_w, knn_b, keyworld, mf);

    fuse_kernel<<<(BB * NK) / KPB, 256, 0, stream>>>(
        fusion_feat, tki, kw_w1, kw_g1, kw_b1, kw_w2, kw_b2,
        fuse_w1, fuse_g1, fuse_b1, fuse_w2, fuse_b2, mf, out + OUT0_OFF);
}

// Round 4
// 272.350 us; speedup vs baseline: 1.7396x; 1.0438x over previous
//
#include <hip/hip_runtime.h>
#include <math.h>

#define BB 2
#define NF 20000
#define NS 30000
#define CH 128
#define NK 500
#define KNN 16
#define KPB 4

// grid params: cell = 1.001 * radius (margin vs float boundary rounding)
#define HA 2.4024f
#define HB 4.8048f
#define NCA 45
#define NCB 23
#define CELLS_A 2025
#define CELLS_B 529
#define TOTPTS (2 * BB * NS)

// output offsets (floats, concatenated in return order)
#define OUT0_OFF 0           // out          (B*NK*128) = 128000
#define OUT1_OFF 128000      // key_voxel_indices (B*NK*3) = 3000
#define OUT2_OFF 131000      // heat_scores  (B*NF) = 40000
#define OUT3_OFF 171000      // scores10     (B*NF*10) = 400000
#define OUT4_OFF 571000      // key_class    (B*NK) = 1000

// workspace offsets (bytes)
#define WS_CLS   0           // int32  x 40000
#define WS_TKI   160000      // int32  x 1000
#define WS_KW    164000      // float  x 2000
#define WS_MF    172000      // float  x 256000 (1,024,000 B)
#define WS_KEYS  WS_MF       // u64 x 40000 overlays mf (temporally disjoint)
#define WS_GSTART 1196000    // int x 5112 (cell starts, +1 per (s,b))
#define WS_GCUR   1216448    // int x 5108 (counts, then cursors)
#define WS_PTS    1236880    // float2 x 120000 (sorted world coords)
#define WS_PIDX   2196880    // int x 120000 (sorted original indices)

#define CURB(s,b) ((s) ? (4050 + (b) * 529) : ((b) * 2025))
#define STB(s,b)  ((s) ? (4052 + (b) * 530) : ((b) * 2026))

__device__ __forceinline__ unsigned ordf(float s) {
    unsigned u = __float_as_uint(s);
    return (u & 0x80000000u) ? ~u : (u | 0x80000000u);
}

// ---------------------------------------------------------------------------
// K1: heat MLP, LDS-tiled SGEMM (unchanged from R3).
// ---------------------------------------------------------------------------
__global__ __launch_bounds__(256) void heat_kernel(
    const float* __restrict__ x,
    const float* __restrict__ w1,
    const float* __restrict__ g1, const float* __restrict__ b1,
    const float* __restrict__ w2,
    const float* __restrict__ b2,
    float* __restrict__ out_heat,
    float* __restrict__ out_s10,
    int* __restrict__ cls,
    unsigned long long* __restrict__ keys)
{
    __shared__ float As[64 * 72];
    __shared__ float Ws[64 * 132];
    __shared__ float W2s[1280];
    const int tid = threadIdx.x;
    const int m0 = blockIdx.x * 64;
    const int tx = tid & 15;
    const int ty = tid >> 4;

    for (int v = tid; v < 1280; v += 256) W2s[v] = w2[v];

    float acc[4][8];
#pragma unroll
    for (int i = 0; i < 4; ++i)
#pragma unroll
        for (int j = 0; j < 8; ++j) acc[i][j] = 0.f;

    const float4* xv = (const float4*)x;
    const float4* w1v = (const float4*)w1;

    for (int kc = 0; kc < 128; kc += 64) {
#pragma unroll
        for (int i = 0; i < 4; ++i) {
            int v = tid + i * 256;
            int row = v >> 4, c4 = v & 15;
            float4 val = xv[(size_t)(m0 + row) * 32 + (kc >> 2) + c4];
            *(float4*)&As[row * 72 + c4 * 4] = val;
        }
#pragma unroll
        for (int i = 0; i < 8; ++i) {
            int v = tid + i * 256;
            int k = v >> 5, c4 = v & 31;
            float4 val = w1v[(size_t)(kc + k) * 32 + c4];
            *(float4*)&Ws[k * 132 + c4 * 4] = val;
        }
        __syncthreads();

        const float* a0p = &As[(ty * 4 + 0) * 72];
        const float* a1p = &As[(ty * 4 + 1) * 72];
        const float* a2p = &As[(ty * 4 + 2) * 72];
        const float* a3p = &As[(ty * 4 + 3) * 72];
#pragma unroll 4
        for (int k = 0; k < 64; ++k) {
            float4 bA = *(const float4*)&Ws[k * 132 + tx * 8];
            float4 bB = *(const float4*)&Ws[k * 132 + tx * 8 + 4];
            float a0 = a0p[k], a1 = a1p[k], a2 = a2p[k], a3 = a3p[k];
            acc[0][0] += a0 * bA.x; acc[0][1] += a0 * bA.y; acc[0][2] += a0 * bA.z; acc[0][3] += a0 * bA.w;
            acc[0][4] += a0 * bB.x; acc[0][5] += a0 * bB.y; acc[0][6] += a0 * bB.z; acc[0][7] += a0 * bB.w;
            acc[1][0] += a1 * bA.x; acc[1][1] += a1 * bA.y; acc[1][2] += a1 * bA.z; acc[1][3] += a1 * bA.w;
            acc[1][4] += a1 * bB.x; acc[1][5] += a1 * bB.y; acc[1][6] += a1 * bB.z; acc[1][7] += a1 * bB.w;
            acc[2][0] += a2 * bA.x; acc[2][1] += a2 * bA.y; acc[2][2] += a2 * bA.z; acc[2][3] += a2 * bA.w;
            acc[2][4] += a2 * bB.x; acc[2][5] += a2 * bB.y; acc[2][6] += a2 * bB.z; acc[2][7] += a2 * bB.w;
            acc[3][0] += a3 * bA.x; acc[3][1] += a3 * bA.y; acc[3][2] += a3 * bA.z; acc[3][3] += a3 * bA.w;
            acc[3][4] += a3 * bB.x; acc[3][5] += a3 * bB.y; acc[3][6] += a3 * bB.z; acc[3][7] += a3 * bB.w;
        }
        __syncthreads();
    }

    float4 g1a = ((const float4*)g1)[tx * 2], g1b = ((const float4*)g1)[tx * 2 + 1];
    float4 b1a = ((const float4*)b1)[tx * 2], b1b = ((const float4*)b1)[tx * 2 + 1];
    float* Hs = Ws;
#pragma unroll
    for (int i = 0; i < 4; ++i) {
        int row = ty * 4 + i;
        float4 hA, hB;
        hA.x = fmaxf(acc[i][0] * g1a.x + b1a.x, 0.f);
        hA.y = fmaxf(acc[i][1] * g1a.y + b1a.y, 0.f);
        hA.z = fmaxf(acc[i][2] * g1a.z + b1a.z, 0.f);
        hA.w = fmaxf(acc[i][3] * g1a.w + b1a.w, 0.f);
        hB.x = fmaxf(acc[i][4] * g1b.x + b1b.x, 0.f);
        hB.y = fmaxf(acc[i][5] * g1b.y + b1b.y, 0.f);
        hB.z = fmaxf(acc[i][6] * g1b.z + b1b.z, 0.f);
        hB.w = fmaxf(acc[i][7] * g1b.w + b1b.w, 0.f);
        *(float4*)&Hs[row * 132 + tx * 8] = hA;
        *(float4*)&Hs[row * 132 + tx * 8 + 4] = hB;
    }
    __syncthreads();

    const int r = tid >> 2;
    const int p = tid & 3;
    float a2[10];
#pragma unroll
    for (int c = 0; c < 10; ++c) a2[c] = 0.f;
    for (int kk = 0; kk < 32; ++kk) {
        int k = kk * 4 + p;
        float hv = Hs[r * 132 + k];
#pragma unroll
        for (int c = 0; c < 10; ++c) a2[c] += hv * W2s[k * 10 + c];
    }
#pragma unroll
    for (int c = 0; c < 10; ++c) {
        a2[c] += __shfl_xor(a2[c], 1);
        a2[c] += __shfl_xor(a2[c], 2);
    }
    if (p == 0) {
        int m = m0 + r;
        float best = -INFINITY;
        int bi = 0;
#pragma unroll
        for (int c = 0; c < 10; ++c) {
            float s = a2[c] + b2[c];
            out_s10[(size_t)m * 10 + c] = s;
            if (s > best) { best = s; bi = c; }
        }
        out_heat[m] = best;
        cls[m] = bi;
        int b = m / NF;
        unsigned i = (unsigned)(m - b * NF);
        float sig = 1.0f / (1.0f + expf(-best));
        keys[m] = ((unsigned long long)ordf(sig) << 32) | (unsigned)(~i);
    }
}

// ---------------------------------------------------------------------------
// K2: exact top-500 per batch (unchanged from R3).
// ---------------------------------------------------------------------------
#define H1BINS 16384
#define H2BINS 1024

__global__ __launch_bounds__(1024) void topk_kernel(
    const unsigned long long* __restrict__ keys,
    const int* __restrict__ cls,
    const int* __restrict__ fcoords,
    float* __restrict__ out1,
    float* __restrict__ out4,
    int* __restrict__ tki,
    float* __restrict__ keyworld)
{
    __shared__ unsigned h[H1BINS];
    __shared__ unsigned long long list[1024];
    __shared__ unsigned csum[1024];
    __shared__ unsigned ssum[32];
    __shared__ unsigned sel_s, krem_s, cnt_s;
    const int b = blockIdx.x;
    const int tid = threadIdx.x;
    const unsigned long long* kb = keys + (size_t)b * NF;

    for (int i = tid; i < H1BINS; i += 1024) h[i] = 0u;
    __syncthreads();
#pragma unroll 4
    for (int i = tid; i < NF; i += 1024)
        atomicAdd(&h[(unsigned)(kb[i] >> 50)], 1u);
    __syncthreads();
    {
        unsigned s = 0;
        int base = tid * 16;
#pragma unroll
        for (int j = 0; j < 16; ++j) s += h[base + j];
        csum[tid] = s;
    }
    __syncthreads();
    if (tid < 32) {
        unsigned s = 0;
        for (int j = 0; j < 32; ++j) s += csum[tid * 32 + j];
        ssum[tid] = s;
    }
    __syncthreads();
    if (tid == 0) {
        unsigned K = NK, acc = 0;
        int sidx = 31;
        for (; sidx > 0; --sidx) { if (acc + ssum[sidx] >= K) break; acc += ssum[sidx]; }
        int cidx = sidx * 32 + 31;
        for (;; --cidx) { if (acc + csum[cidx] >= K) break; acc += csum[cidx]; }
        int bin = cidx * 16 + 15;
        for (;; --bin) { if (acc + h[bin] >= K) break; acc += h[bin]; }
        sel_s = (unsigned)bin;
        krem_s = K - acc;
    }
    __syncthreads();
    const unsigned T1 = sel_s;
    const unsigned K2 = krem_s;

    for (int i = tid; i < H2BINS; i += 1024) h[i] = 0u;
    __syncthreads();
#pragma unroll 4
    for (int i = tid; i < NF; i += 1024) {
        unsigned long long key = kb[i];
        if ((unsigned)(key >> 50) == T1)
            atomicAdd(&h[(unsigned)(key >> 40) & 1023u], 1u);
    }
    __syncthreads();
    if (tid < 32) {
        unsigned s = 0;
        for (int j = 0; j < 32; ++j) s += h[tid * 32 + j];
        csum[tid] = s;
    }
    __syncthreads();
    if (tid == 0) {
        unsigned acc = 0;
        int cidx = 31;
        for (; cidx > 0; --cidx) { if (acc + csum[cidx] >= K2) break; acc += csum[cidx]; }
        int bin = cidx * 32 + 31;
        for (;; --bin) { if (acc + h[bin] >= K2) break; acc += h[bin]; }
        sel_s = (T1 << 10) | (unsigned)bin;
        cnt_s = 0u;
    }
    __syncthreads();
    const unsigned thr24 = sel_s;

#pragma unroll 4
    for (int i = tid; i < NF; i += 1024) {
        unsigned long long key = kb[i];
        if ((unsigned)(key >> 40) >= thr24) {
            unsigned pos = atomicAdd(&cnt_s, 1u);
            if (pos < 1024u) list[pos] = key;
        }
    }
    __syncthreads();
    unsigned cc = cnt_s > 1024u ? 1024u : cnt_s;
    if ((unsigned)tid >= cc) list[tid] = 0ull;
    __syncthreads();

    for (int kk = 2; kk <= 1024; kk <<= 1) {
        for (int j = kk >> 1; j > 0; j >>= 1) {
            int i = tid, ixj = i ^ j;
            if (ixj > i) {
                unsigned long long a = list[i], bv = list[ixj];
                bool up = ((i & kk) == 0);
                if (up ? (a < bv) : (a > bv)) { list[i] = bv; list[ixj] = a; }
            }
            __syncthreads();
        }
    }

    if (tid < NK) {
        unsigned long long key = list[tid];
        int idx = (int)(~(unsigned)(key & 0xFFFFFFFFull));
        tki[b * NK + tid] = idx;
        int c0 = fcoords[((size_t)b * NF + idx) * 2 + 0];
        int c1 = fcoords[((size_t)b * NF + idx) * 2 + 1];
        size_t o = (size_t)(b * NK + tid);
        out1[o * 3 + 0] = (float)b;
        out1[o * 3 + 1] = (float)c0;
        out1[o * 3 + 2] = (float)c1;
        float wx = __fadd_rn(__fmul_rn(__fmul_rn(__fadd_rn((float)c0, 0.5f), 8.0f), 0.075f), -54.0f);
        float wy = __fadd_rn(__fmul_rn(__fmul_rn(__fadd_rn((float)c1, 0.5f), 8.0f), 0.075f), -54.0f);
        keyworld[o * 2 + 0] = wx;
        keyworld[o * 2 + 1] = wy;
        out4[o] = (float)cls[(size_t)b * NF + idx];
    }
}

// ---------------------------------------------------------------------------
// Grid build: zero -> count -> scan -> scatter. World transform in count and
// scatter is the exact expression the old knn used, so d2 is bit-identical.
// ---------------------------------------------------------------------------
__global__ void grid_zero(int* __restrict__ gcur) {
    int i = blockIdx.x * 1024 + threadIdx.x;
    if (i < 5108) gcur[i] = 0;
}

__device__ __forceinline__ void point_world_cell(
    const int* sca, const int* scb, int g, float& sx, float& sy,
    int& s, int& b, int& i, int& cell)
{
    s = g / (BB * NS);
    int rem = g - s * (BB * NS);
    b = rem / NS;
    i = rem - b * NS;
    const int2* sc = ((const int2*)(s ? scb : sca)) + (size_t)b * NS;
    int2 c = sc[i];
    float stride = s ? 8.0f : 4.0f;
    sx = __fadd_rn(__fmul_rn(__fmul_rn(__fadd_rn((float)c.x, 0.5f), stride), 0.075f), -54.0f);
    sy = __fadd_rn(__fmul_rn(__fmul_rn(__fadd_rn((float)c.y, 0.5f), stride), 0.075f), -54.0f);
    float inv_h = s ? (1.0f / HB) : (1.0f / HA);
    int nc = s ? NCB : NCA;
    int cx = (int)floorf((sx + 54.0f) * inv_h);
    int cy = (int)floorf((sy + 54.0f) * inv_h);
    cx = min(max(cx, 0), nc - 1);
    cy = min(max(cy, 0), nc - 1);
    cell = cy * nc + cx;
}

__global__ __launch_bounds__(256) void grid_count(
    const int* __restrict__ sca, const int* __restrict__ scb,
    int* __restrict__ gcur)
{
    int g = blockIdx.x * 256 + threadIdx.x;
    if (g >= TOTPTS) return;
    float sx, sy; int s, b, i, cell;
    point_world_cell(sca, scb, g, sx, sy, s, b, i, cell);
    atomicAdd(&gcur[CURB(s, b) + cell], 1);
}

__global__ __launch_bounds__(1024) void grid_scan(
    int* __restrict__ gcur, int* __restrict__ gstart)
{
    __shared__ int t0[1024], t1[1024];
    const int sb = blockIdx.x;
    const int s = sb >> 1, b = sb & 1;
    const int n = s ? CELLS_B : CELLS_A;
    const int curb = CURB(s, b);
    const int stb = STB(s, b);
    const int tid = threadIdx.x;
    int i0 = tid * 2, i1 = tid * 2 + 1;
    int c0 = (i0 < n) ? gcur[curb + i0] : 0;
    int c1 = (i1 < n) ? gcur[curb + i1] : 0;
    t0[tid] = c0 + c1;
    __syncthreads();
    int* src = t0; int* dst = t1;
    for (int off = 1; off < 1024; off <<= 1) {
        int v = src[tid];
        if (tid >= off) v += src[tid - off];
        dst[tid] = v;
        __syncthreads();
        int* tmp = src; src = dst; dst = tmp;
    }
    int excl = (tid == 0) ? 0 : src[tid - 1];
    if (i0 < n) { gstart[stb + i0] = excl; gcur[curb + i0] = excl; }
    if (i1 < n) { gstart[stb + i1] = excl + c0; gcur[curb + i1] = excl + c0; }
    if (tid == 0) gstart[stb + n] = NS;
}

__global__ __launch_bounds__(256) void grid_scatter(
    const int* __restrict__ sca, const int* __restrict__ scb,
    int* __restrict__ gcur, float2* __restrict__ pts, int* __restrict__ pidx)
{
    int g = blockIdx.x * 256 + threadIdx.x;
    if (g >= TOTPTS) return;
    float sx, sy; int s, b, i, cell;
    point_world_cell(sca, scb, g, sx, sy, s, b, i, cell);
    int pos = atomicAdd(&gcur[CURB(s, b) + cell], 1);
    size_t base = ((size_t)s * BB + b) * NS;
    pts[base + pos] = make_float2(sx, sy);
    pidx[base + pos] = i;
}

// ---------------------------------------------------------------------------
// K3: grid-accelerated radius-KNN. One block per (s,b,key). Scans 3 row-
// contiguous cell ranges (3x3 cells), pushes in-radius hits, bitonic-sorts
// (d2 asc, idx asc) 64-bit keys, then gathers the 16-neighbor weighted sum.
// ---------------------------------------------------------------------------
__global__ __launch_bounds__(256) void knn_kernel(
    const float* __restrict__ sfa, const float* __restrict__ sfb,
    const int* __restrict__ gstart,
    const float2* __restrict__ pts, const int* __restrict__ pidx,
    const float* __restrict__ knn_w,
    const float* __restrict__ knn_b,
    const float* __restrict__ keyworld,
    float* __restrict__ mf)
{
    __shared__ unsigned long long list[1024];
    __shared__ unsigned cnt_s;
    const int tid = threadIdx.x;
    const int blk = blockIdx.x;
    const int s = blk / (BB * NK);
    const int rest = blk % (BB * NK);
    const int b = rest / NK;
    const int r = rest % NK;
    const float* sfeat = s ? sfb : sfa;
    const float r2 = s ? (float)(4.8 * 4.8) : (float)(2.4 * 2.4);
    const float inv_h = s ? (1.0f / HB) : (1.0f / HA);
    const int nc = s ? NCB : NCA;
    const int stb = STB(s, b);
    const size_t pbase = ((size_t)s * BB + b) * NS;

    if (tid == 0) cnt_s = 0u;
    __syncthreads();
    const float kx = keyworld[((size_t)b * NK + r) * 2 + 0];
    const float ky = keyworld[((size_t)b * NK + r) * 2 + 1];
    int cx = (int)floorf((kx + 54.0f) * inv_h);
    int cy = (int)floorf((ky + 54.0f) * inv_h);
    cx = min(max(cx, 0), nc - 1);
    cy = min(max(cy, 0), nc - 1);
    const int c0 = max(cx - 1, 0), c1 = min(cx + 1, nc - 1);
    const int cy0 = max(cy - 1, 0), cy1 = min(cy + 1, nc - 1);

    for (int cyy = cy0; cyy <= cy1; ++cyy) {
        int lo = gstart[stb + cyy * nc + c0];
        int hi = gstart[stb + cyy * nc + c1 + 1];
        for (int p = lo + tid; p < hi; p += 256) {
            float2 w = pts[pbase + p];
            float dx = __fsub_rn(kx, w.x);
            float dy = __fsub_rn(ky, w.y);
            float d2 = __fadd_rn(__fmul_rn(dx, dx), __fmul_rn(dy, dy));
            if (d2 <= r2) {
                unsigned pos = atomicAdd(&cnt_s, 1u);
                if (pos < 1024u)
                    list[pos] = ((unsigned long long)__float_as_uint(d2) << 32)
                              | (unsigned)pidx[pbase + p];
            }
        }
    }
    __syncthreads();
    int cc = (int)cnt_s;
    if (cc > 1024) cc = 1024;
    int n2 = 16;
    while (n2 < cc) n2 <<= 1;
    for (int i = tid; i < n2; i += 256)
        if (i >= cc) list[i] = ~0ull;
    __syncthreads();
    for (int kk = 2; kk <= n2; kk <<= 1) {
        for (int j = kk >> 1; j > 0; j >>= 1) {
            for (int i = tid; i < n2; i += 256) {
                int ixj = i ^ j;
                if (ixj > i) {
                    unsigned long long a = list[i], bv = list[ixj];
                    bool up = ((i & kk) == 0);
                    bool sw = up ? (a > bv) : (a < bv);
                    if (sw) { list[i] = bv; list[ixj] = a; }
                }
            }
            __syncthreads();
        }
    }
    if (tid < CH) {
        float acc = knn_b[s];
        int K = cc < KNN ? cc : KNN;
        for (int k = 0; k < K; ++k) {
            unsigned i = (unsigned)(list[k] & 0xFFFFFFFFull);
            acc += knn_w[s * 16 + k] * sfeat[((size_t)b * NS + i) * CH + tid];
        }
        mf[(((size_t)s * BB + b) * NK + r) * CH + tid] = acc;
    }
}

// ---------------------------------------------------------------------------
// K4: fuse MLP, 4 keys per block (unchanged from R3).
// ---------------------------------------------------------------------------
__global__ __launch_bounds__(256) void fuse_kernel(
    const float* __restrict__ ffeat,
    const int* __restrict__ tki,
    const float* __restrict__ kw_w1, const float* __restrict__ kw_g1,
    const float* __restrict__ kw_b1, const float* __restrict__ kw_w2,
    const float* __restrict__ kw_b2,
    const float* __restrict__ fuse_w1, const float* __restrict__ fuse_g1,
    const float* __restrict__ fuse_b1, const float* __restrict__ fuse_w2,
    const float* __restrict__ fuse_b2,
    const float* __restrict__ mf,
    float* __restrict__ out0)
{
    __shared__ float xs[KPB * 128];
    __shared__ float hsX[KPB * 64];
    __shared__ float l3[KPB * 3];
    __shared__ float wsm[KPB * 2];
    __shared__ float fusedv[KPB * 256];
    __shared__ float h2s[KPB * 256];
    __shared__ int idxs[KPB], bs[KPB], rs[KPB];
    const int tid = threadIdx.x;
    const int f0 = blockIdx.x * KPB;

    if (tid < KPB) {
        int flat = f0 + tid;
        int b = flat / NK;
        bs[tid] = b;
        rs[tid] = flat - b * NK;
        idxs[tid] = tki[flat];
    }
    __syncthreads();
    for (int v = tid; v < KPB * 128; v += 256) {
        int key = v >> 7, c = v & 127;
        xs[v] = ffeat[((size_t)bs[key] * NF + idxs[key]) * CH + c];
    }
    __syncthreads();
    if (tid < 64) {
        float h[KPB] = {0.f, 0.f, 0.f, 0.f};
        for (int k = 0; k < 128; ++k) {
            float wv = kw_w1[k * 64 + tid];
#pragma unroll
            for (int j = 0; j < KPB; ++j) h[j] += xs[j * 128 + k] * wv;
        }
        float g = kw_g1[tid], bb = kw_b1[tid];
#pragma unroll
        for (int j = 0; j < KPB; ++j) {
            float t = h[j] * g + bb;
            hsX[j * 64 + tid] = t > 0.f ? t : 0.f;
        }
    }
    __syncthreads();
    if (tid < KPB * 3) {
        int key = tid / 3, jj = tid - key * 3;
        float l = 0.f;
        for (int k = 0; k < 64; ++k) l += hsX[key * 64 + k] * kw_w2[k * 3 + jj];
        l3[key * 3 + jj] = l + kw_b2[jj];
    }
    __syncthreads();
    if (tid < KPB) {
        float l0 = l3[tid * 3], l1 = l3[tid * 3 + 1], l2 = l3[tid * 3 + 2];
        float m = fmaxf(l0, fmaxf(l1, l2));
        float e0 = expf(l0 - m), e1 = expf(l1 - m), e2 = expf(l2 - m);
        float sum = e0 + e1 + e2;
        wsm[tid * 2 + 0] = e0 / sum;
        wsm[tid * 2 + 1] = e1 / sum;
    }
    __syncthreads();
    for (int v = tid; v < KPB * 256; v += 256) {
        int key = v >> 8, c = v & 255;
        float w0 = wsm[key * 2], w1_ = wsm[key * 2 + 1];
        if (c < 128) {
            int b = bs[key], r = rs[key];
            float xv_ = xs[key * 128 + c];
            float m0 = mf[(((size_t)0 * BB + b) * NK + r) * CH + c];
            float m1 = mf[(((size_t)1 * BB + b) * NK + r) * CH + c];
            float kv = w0 * xv_;
            float fs = kv * m0;
            float kv2 = w1_ * kv;
            fusedv[v] = fs + kv2 * m1;
        } else {
            float xv_ = xs[key * 128 + (c - 128)];
            float kv = w0 * xv_;
            fusedv[v] = w1_ * kv;
        }
    }
    __syncthreads();
    {
        float acc4[KPB] = {0.f, 0.f, 0.f, 0.f};
        for (int k = 0; k < 256; ++k) {
            float wv = fuse_w1[k * 256 + tid];
#pragma unroll
            for (int j = 0; j < KPB; ++j) acc4[j] += fusedv[j * 256 + k] * wv;
        }
        float g = fuse_g1[tid], bb = fuse_b1[tid];
#pragma unroll
        for (int j = 0; j < KPB; ++j) {
            float t = acc4[j] * g + bb;
            h2s[j * 256 + tid] = t > 0.f ? t : 0.f;
        }
    }
    __syncthreads();
    if (tid < 128) {
        float o[KPB];
        float bb = fuse_b2[tid];
#pragma unroll
        for (int j = 0; j < KPB; ++j) o[j] = bb;
        for (int k = 0; k < 256; ++k) {
            float wv = fuse_w2[k * 128 + tid];
#pragma unroll
            for (int j = 0; j < KPB; ++j) o[j] += h2s[j * 256 + k] * wv;
        }
#pragma unroll
        for (int j = 0; j < KPB; ++j)
            out0[((size_t)bs[j] * NK + rs[j]) * CH + tid] = o[j];
    }
}

extern "C" void kernel_launch(void* const* d_in, const int* in_sizes, int n_in,
                              void* d_out, int out_size, void* d_ws, size_t ws_size,
                              hipStream_t stream)
{
    const float* fusion_feat = (const float*)d_in[0];
    const float* src_feat_a  = (const float*)d_in[1];
    const float* src_feat_b  = (const float*)d_in[2];
    const float* heat_w1 = (const float*)d_in[3];
    const float* heat_g1 = (const float*)d_in[4];
    const float* heat_b1 = (const float*)d_in[5];
    const float* heat_w2 = (const float*)d_in[6];
    const float* heat_b2 = (const float*)d_in[7];
    const float* knn_w   = (const float*)d_in[8];
    const float* knn_b   = (const float*)d_in[9];
    const float* kw_w1   = (const float*)d_in[10];
    const float* kw_g1   = (const float*)d_in[11];
    const float* kw_b1   = (const float*)d_in[12];
    const float* kw_w2   = (const float*)d_in[13];
    const float* kw_b2   = (const float*)d_in[14];
    const float* fuse_w1 = (const float*)d_in[15];
    const float* fuse_g1 = (const float*)d_in[16];
    const float* fuse_b1 = (const float*)d_in[17];
    const float* fuse_w2 = (const float*)d_in[18];
    const float* fuse_b2 = (const float*)d_in[19];
    const int* fusion_coords = (const int*)d_in[20];
    const int* src_coords_a  = (const int*)d_in[21];
    const int* src_coords_b  = (const int*)d_in[22];

    float* out = (float*)d_out;
    char* ws = (char*)d_ws;
    int* cls = (int*)(ws + WS_CLS);
    int* tki = (int*)(ws + WS_TKI);
    float* keyworld = (float*)(ws + WS_KW);
    float* mf = (float*)(ws + WS_MF);
    unsigned long long* keys = (unsigned long long*)(ws + WS_KEYS);
    int* gstart = (int*)(ws + WS_GSTART);
    int* gcur = (int*)(ws + WS_GCUR);
    float2* pts = (float2*)(ws + WS_PTS);
    int* pidx = (int*)(ws + WS_PIDX);

    heat_kernel<<<(BB * NF) / 64, 256, 0, stream>>>(
        fusion_feat, heat_w1, heat_g1, heat_b1, heat_w2, heat_b2,
        out + OUT2_OFF, out + OUT3_OFF, cls, keys);

    topk_kernel<<<BB, 1024, 0, stream>>>(
        keys, cls, fusion_coords,
        out + OUT1_OFF, out + OUT4_OFF, tki, keyworld);

    grid_zero<<<5, 1024, 0, stream>>>(gcur);
    grid_count<<<(TOTPTS + 255) / 256, 256, 0, stream>>>(src_coords_a, src_coords_b, gcur);
    grid_scan<<<4, 1024, 0, stream>>>(gcur, gstart);
    grid_scatter<<<(TOTPTS + 255) / 256, 256, 0, stream>>>(src_coords_a, src_coords_b, gcur, pts, pidx);

    knn_kernel<<<2 * BB * NK, 256, 0, stream>>>(
        src_feat_a, src_feat_b, gstart, pts, pidx,
        knn_w, knn_b, keyworld, mf);

    fuse_kernel<<<(BB * NK) / KPB, 256, 0, stream>>>(
        fusion_feat, tki, kw_w1, kw_g1, kw_b1, kw_w2, kw_b2,
        fuse_w1, fuse_g1, fuse_b1, fuse_w2, fuse_b2, mf, out + OUT0_OFF);
}